// Round 2
// baseline (861.073 us; speedup 1.0000x reference)
//
#include <hip/hip_runtime.h>
#include <math.h>

#define E 16
#define D 64
#define H 128
#define R 2            // n-rows per block
#define ROWS (R * E)   // 32 expert-rows per block

// ---------------------------------------------------------------------------
// Prep: Wabc[c][j] = Wa + Wb + Wc  (spec_W1 rows 0..127, 128..255, 256..383)
// ---------------------------------------------------------------------------
__global__ void wabc_prep(const float* __restrict__ specW1, float* __restrict__ wabc) {
    int i = blockIdx.x * blockDim.x + threadIdx.x;
    if (i < H * H) {
        wabc[i] = specW1[i] + specW1[H * H + i] + specW1[2 * H * H + i];
    }
}

__device__ inline float waveReduceSum(float v) {
#pragma unroll
    for (int off = 32; off; off >>= 1) v += __shfl_xor(v, off, 64);
    return v;
}

// ---------------------------------------------------------------------------
// Fused router. Block = 256 threads, R=2 rows. LDS buffers aliased by
// lifetime: bufA = tokens (stages 1-2) -> encoded (stage 3+); bufB = h
// (stages 2-3) -> absdelta (stage 4+). 35 KB LDS -> 4 blocks/CU (16 waves).
// ---------------------------------------------------------------------------
template <bool USE_WABC>
__global__ __launch_bounds__(256, 4)
void router_kernel(const float* __restrict__ tokens,
                   const float* __restrict__ encW1, const float* __restrict__ encB1,
                   const float* __restrict__ encW2, const float* __restrict__ encB2,
                   const float* __restrict__ specW1, const float* __restrict__ specB1,
                   const float* __restrict__ specW2,
                   const float* __restrict__ defW1, const float* __restrict__ defB1,
                   const float* __restrict__ defW2, const float* __restrict__ defB2,
                   const int* __restrict__ fiPtr, const int* __restrict__ tkPtr,
                   const float* __restrict__ wabc,
                   float* __restrict__ out, int N) {
    __shared__ float bufA[ROWS * H];    // 16 KB: tokens (first 8 KB) -> encoded
    __shared__ float bufB[ROWS * H];    // 16 KB: h -> absdelta
    __shared__ float s_glob[R * H];
    __shared__ float s_mabs[R * H];
    __shared__ float s_bias[R * H];
    __shared__ float s_logits[ROWS];
    __shared__ float s_dred[4];

    const int tid   = threadIdx.x;
    const int n0    = blockIdx.x * R;
    const int fi    = fiPtr[0];
    const int lane  = tid & 63;
    const int wq    = tid >> 6;        // wave 0..3
    const int j0    = lane * 2;        // 0..126 even
    const int mbase = wq * 8;          // expert-row block for GEMM stages

    // ---- stage 1: load tokens (ROWS*D = 2048 floats) into bufA ----
    {
        const size_t base  = (size_t)n0 * (E * D);
        const size_t total = (size_t)N * (E * D);
        float4* dst = (float4*)bufA;
#pragma unroll
        for (int it = 0; it < 2; it++) {
            int f = tid + it * 256;
            size_t off = base + (size_t)f * 4;
            float4 v = make_float4(0.f, 0.f, 0.f, 0.f);
            if (off + 3 < total) v = *(const float4*)(tokens + off);
            dst[f] = v;
        }
    }
    __syncthreads();

    // ---- stage 2: enc1  h = relu(tok @ W1 + b1), K=64; bufA -> bufB ----
    {
        float acc[8][2];
#pragma unroll
        for (int m = 0; m < 8; m++) { acc[m][0] = 0.f; acc[m][1] = 0.f; }
#pragma unroll 2
        for (int k = 0; k < D; k += 4) {
            float2 w0 = *(const float2*)(encW1 + (k + 0) * H + j0);
            float2 w1 = *(const float2*)(encW1 + (k + 1) * H + j0);
            float2 w2 = *(const float2*)(encW1 + (k + 2) * H + j0);
            float2 w3 = *(const float2*)(encW1 + (k + 3) * H + j0);
#pragma unroll
            for (int m = 0; m < 8; m++) {
                float4 t = *(const float4*)(bufA + (mbase + m) * D + k);
                acc[m][0] = fmaf(t.w, w3.x, fmaf(t.z, w2.x, fmaf(t.y, w1.x, fmaf(t.x, w0.x, acc[m][0]))));
                acc[m][1] = fmaf(t.w, w3.y, fmaf(t.z, w2.y, fmaf(t.y, w1.y, fmaf(t.x, w0.y, acc[m][1]))));
            }
        }
        float2 b = *(const float2*)(encB1 + j0);
#pragma unroll
        for (int m = 0; m < 8; m++) {
            float2 o;
            o.x = fmaxf(acc[m][0] + b.x, 0.f);
            o.y = fmaxf(acc[m][1] + b.y, 0.f);
            *(float2*)(bufB + (mbase + m) * H + j0) = o;
        }
    }
    __syncthreads();

    // ---- stage 3: enc2  encoded = relu(h @ W2 + b2), K=128; bufB -> bufA ----
    {
        float acc[8][2];
#pragma unroll
        for (int m = 0; m < 8; m++) { acc[m][0] = 0.f; acc[m][1] = 0.f; }
#pragma unroll 2
        for (int k = 0; k < H; k += 4) {
            float2 w0 = *(const float2*)(encW2 + (k + 0) * H + j0);
            float2 w1 = *(const float2*)(encW2 + (k + 1) * H + j0);
            float2 w2 = *(const float2*)(encW2 + (k + 2) * H + j0);
            float2 w3 = *(const float2*)(encW2 + (k + 3) * H + j0);
#pragma unroll
            for (int m = 0; m < 8; m++) {
                float4 t = *(const float4*)(bufB + (mbase + m) * H + k);
                acc[m][0] = fmaf(t.w, w3.x, fmaf(t.z, w2.x, fmaf(t.y, w1.x, fmaf(t.x, w0.x, acc[m][0]))));
                acc[m][1] = fmaf(t.w, w3.y, fmaf(t.z, w2.y, fmaf(t.y, w1.y, fmaf(t.x, w0.y, acc[m][1]))));
            }
        }
        float2 b = *(const float2*)(encB2 + j0);
#pragma unroll
        for (int m = 0; m < 8; m++) {
            float2 o;
            o.x = fmaxf(acc[m][0] + b.x, 0.f);
            o.y = fmaxf(acc[m][1] + b.y, 0.f);
            *(float2*)(bufA + (mbase + m) * H + j0) = o;
        }
    }
    __syncthreads();

    // ---- stage 4: stats: glob mean, absdelta (bufA -> bufB), mean|delta| ----
    {
        const int r = tid >> 7;     // 0..1
        const int c = tid & 127;
        const float* er = bufA + (r * E) * H + c;
        float s = 0.f;
#pragma unroll
        for (int e = 0; e < E; e++) s += er[e * H];
        float g  = s * (1.f / 16.f);
        float fc = er[fi * H];
        float ma = 0.f;
#pragma unroll
        for (int e = 0; e < E; e++) {
            float d = er[e * H] - fc;
            float a = fabsf(d);
            bufB[(r * E + e) * H + c] = a;
            ma += a;
        }
        s_glob[r * H + c] = g;
        s_mabs[r * H + c] = ma * (1.f / 16.f);
    }
    __syncthreads();

    // ---- stage 5+7 merged: per-n bias GEMV and def-head GEMV ----
    {
        const int r = tid >> 7;
        const int j = tid & 127;
        const float* fr = bufA + (r * E + fi) * H;   // full token (encoded)
        const float* gr = s_glob + r * H;
        const float* mr = s_mabs + r * H;
        float accB = specB1[j];
        float accD = defB1[j];
        for (int c = 0; c < H; c += 4) {
            float4 f4 = *(const float4*)(fr + c);
            float4 g4 = *(const float4*)(gr + c);
            float4 m4 = *(const float4*)(mr + c);
            // bias = spec_b1 - full@Wb - glob@Wc
            accB -= f4.x * specW1[(H + c + 0) * H + j];
            accB -= f4.y * specW1[(H + c + 1) * H + j];
            accB -= f4.z * specW1[(H + c + 2) * H + j];
            accB -= f4.w * specW1[(H + c + 3) * H + j];
            accB -= g4.x * specW1[(2 * H + c + 0) * H + j];
            accB -= g4.y * specW1[(2 * H + c + 1) * H + j];
            accB -= g4.z * specW1[(2 * H + c + 2) * H + j];
            accB -= g4.w * specW1[(2 * H + c + 3) * H + j];
            // def head over [full, glob, meanabs]
            accD = fmaf(f4.x, defW1[(c + 0) * H + j], accD);
            accD = fmaf(f4.y, defW1[(c + 1) * H + j], accD);
            accD = fmaf(f4.z, defW1[(c + 2) * H + j], accD);
            accD = fmaf(f4.w, defW1[(c + 3) * H + j], accD);
            accD = fmaf(g4.x, defW1[(H + c + 0) * H + j], accD);
            accD = fmaf(g4.y, defW1[(H + c + 1) * H + j], accD);
            accD = fmaf(g4.z, defW1[(H + c + 2) * H + j], accD);
            accD = fmaf(g4.w, defW1[(H + c + 3) * H + j], accD);
            accD = fmaf(m4.x, defW1[(2 * H + c + 0) * H + j], accD);
            accD = fmaf(m4.y, defW1[(2 * H + c + 1) * H + j], accD);
            accD = fmaf(m4.z, defW1[(2 * H + c + 2) * H + j], accD);
            accD = fmaf(m4.w, defW1[(2 * H + c + 3) * H + j], accD);
        }
        s_bias[r * H + j] = accB;
        float dh = fmaxf(accD, 0.f);
        float v  = dh * defW2[j];
        v = waveReduceSum(v);
        if (lane == 0) s_dred[wq] = v;
    }
    __syncthreads();

    // ---- stage 6: spec GEMM: spec_h = relu(enc@Wabc + absd@Wd + bias); logits ----
    {
        float acc[8][2];
#pragma unroll
        for (int m = 0; m < 8; m++) { acc[m][0] = 0.f; acc[m][1] = 0.f; }
        const int rr = wq >> 1;  // n-row of this wave
        for (int c = 0; c < H; c += 4) {
            float2 wa0, wa1, wa2, wa3;
            if (USE_WABC) {
                wa0 = *(const float2*)(wabc + (c + 0) * H + j0);
                wa1 = *(const float2*)(wabc + (c + 1) * H + j0);
                wa2 = *(const float2*)(wabc + (c + 2) * H + j0);
                wa3 = *(const float2*)(wabc + (c + 3) * H + j0);
            } else {
#pragma unroll
                for (int t = 0; t < 4; t++) {
                    float2 a0 = *(const float2*)(specW1 + (c + t) * H + j0);
                    float2 a1 = *(const float2*)(specW1 + (H + c + t) * H + j0);
                    float2 a2 = *(const float2*)(specW1 + (2 * H + c + t) * H + j0);
                    float2 s2; s2.x = a0.x + a1.x + a2.x; s2.y = a0.y + a1.y + a2.y;
                    if (t == 0) wa0 = s2; else if (t == 1) wa1 = s2; else if (t == 2) wa2 = s2; else wa3 = s2;
                }
            }
            float2 wd0 = *(const float2*)(specW1 + (3 * H + c + 0) * H + j0);
            float2 wd1 = *(const float2*)(specW1 + (3 * H + c + 1) * H + j0);
            float2 wd2 = *(const float2*)(specW1 + (3 * H + c + 2) * H + j0);
            float2 wd3 = *(const float2*)(specW1 + (3 * H + c + 3) * H + j0);
#pragma unroll
            for (int m = 0; m < 8; m++) {
                float4 ev = *(const float4*)(bufA + (mbase + m) * H + c);
                float4 av = *(const float4*)(bufB + (mbase + m) * H + c);
                float a0 = acc[m][0], a1 = acc[m][1];
                a0 = fmaf(ev.x, wa0.x, a0); a0 = fmaf(ev.y, wa1.x, a0);
                a0 = fmaf(ev.z, wa2.x, a0); a0 = fmaf(ev.w, wa3.x, a0);
                a0 = fmaf(av.x, wd0.x, a0); a0 = fmaf(av.y, wd1.x, a0);
                a0 = fmaf(av.z, wd2.x, a0); a0 = fmaf(av.w, wd3.x, a0);
                a1 = fmaf(ev.x, wa0.y, a1); a1 = fmaf(ev.y, wa1.y, a1);
                a1 = fmaf(ev.z, wa2.y, a1); a1 = fmaf(ev.w, wa3.y, a1);
                a1 = fmaf(av.x, wd0.y, a1); a1 = fmaf(av.y, wd1.y, a1);
                a1 = fmaf(av.z, wd2.y, a1); a1 = fmaf(av.w, wd3.y, a1);
                acc[m][0] = a0; acc[m][1] = a1;
            }
        }
        float2 bn = *(const float2*)(s_bias + rr * H + j0);
        float2 w2 = *(const float2*)(specW2 + j0);
#pragma unroll
        for (int m = 0; m < 8; m++) {
            float h0 = fmaxf(acc[m][0] + bn.x, 0.f);
            float h1 = fmaxf(acc[m][1] + bn.y, 0.f);
            float p  = h0 * w2.x + h1 * w2.y;   // spec_b2 dropped: softmax shift-invariant
            p = waveReduceSum(p);
            if (lane == 0) s_logits[mbase + m] = p;
        }
    }
    __syncthreads();

    // ---- stage 8: finalize (2 threads: one per n-row) ----
    if (tid < R && (n0 + tid) < N) {
        const int r = tid;
        const int n = n0 + r;
        // defer prob
        float s = s_dred[2 * r] + s_dred[2 * r + 1] + defB2[0];
        out[(size_t)N * E + n] = 1.f / (1.f + expf(-s));
        // top-k selection (fi excluded; strict > matches lax.top_k tie order)
        int k = tkPtr[0];
        if (k < 1) k = 1;
        if (k > E - 1) k = E - 1;
        unsigned chosen = 0u;
        for (int kk = 0; kk < k; kk++) {
            float bv = -INFINITY;
            int bi = 0;
            for (int e = 0; e < E; e++) {
                if (e == fi || ((chosen >> e) & 1u)) continue;
                float v = s_logits[r * E + e];
                if (v > bv) { bv = v; bi = e; }
            }
            chosen |= (1u << bi);
        }
        float mx = -INFINITY;
        for (int e = 0; e < E; e++)
            if ((chosen >> e) & 1u) { float v = s_logits[r * E + e]; if (v > mx) mx = v; }
        float ssum = 0.f;
        for (int e = 0; e < E; e++)
            if ((chosen >> e) & 1u) ssum += expf(s_logits[r * E + e] - mx);
        float inv = 1.f / ssum;
        for (int e = 0; e < E; e++) {
            float wv = 0.f;
            if ((chosen >> e) & 1u) wv = expf(s_logits[r * E + e] - mx) * inv;
            out[(size_t)n * E + e] = wv;
        }
    }
}

extern "C" void kernel_launch(void* const* d_in, const int* in_sizes, int n_in,
                              void* d_out, int out_size, void* d_ws, size_t ws_size,
                              hipStream_t stream) {
    (void)n_in; (void)out_size;
    const float* tokens = (const float*)d_in[0];
    const float* encW1  = (const float*)d_in[1];
    const float* encB1  = (const float*)d_in[2];
    const float* encW2  = (const float*)d_in[3];
    const float* encB2  = (const float*)d_in[4];
    const float* specW1 = (const float*)d_in[5];
    const float* specB1 = (const float*)d_in[6];
    const float* specW2 = (const float*)d_in[7];
    // d_in[8] = spec_b2 (unused: softmax is shift-invariant)
    const float* defW1  = (const float*)d_in[9];
    const float* defB1  = (const float*)d_in[10];
    const float* defW2  = (const float*)d_in[11];
    const float* defB2  = (const float*)d_in[12];
    const int*   fiPtr  = (const int*)d_in[13];
    const int*   tkPtr  = (const int*)d_in[14];
    float* out = (float*)d_out;

    const int N = in_sizes[0] / (E * D);
    const int grid = (N + R - 1) / R;
    const bool useWs = (d_ws != nullptr) && (ws_size >= (size_t)(H * H * sizeof(float)));

    if (useWs) {
        wabc_prep<<<(H * H + 255) / 256, 256, 0, stream>>>(specW1, (float*)d_ws);
        router_kernel<true><<<grid, 256, 0, stream>>>(
            tokens, encW1, encB1, encW2, encB2, specW1, specB1, specW2,
            defW1, defB1, defW2, defB2, fiPtr, tkPtr, (const float*)d_ws, out, N);
    } else {
        router_kernel<false><<<grid, 256, 0, stream>>>(
            tokens, encW1, encB1, encW2, encB2, specW1, specB1, specW2,
            defW1, defB1, defW2, defB2, fiPtr, tkPtr, nullptr, out, N);
    }
}

// Round 3
// 761.165 us; speedup vs baseline: 1.1313x; 1.1313x over previous
//
#include <hip/hip_runtime.h>
#include <math.h>

#define E 16
#define D 64
#define H 128
#define R 4            // n-rows per block
#define ROWS (R * E)   // 64 expert-rows per block
#define MW 16          // expert-rows per wave

// ---------------------------------------------------------------------------
// Prep: Wabc[c][j] = Wa + Wb + Wc  (spec_W1 rows 0..127, 128..255, 256..383)
// ---------------------------------------------------------------------------
__global__ void wabc_prep(const float* __restrict__ specW1, float* __restrict__ wabc) {
    int i = blockIdx.x * blockDim.x + threadIdx.x;
    if (i < H * H) {
        wabc[i] = specW1[i] + specW1[H * H + i] + specW1[2 * H * H + i];
    }
}

__device__ inline float waveReduceSum(float v) {
#pragma unroll
    for (int off = 32; off; off >>= 1) v += __shfl_xor(v, off, 64);
    return v;
}

// ---------------------------------------------------------------------------
// Fused router. Block = 256 threads (4 waves), R=4 rows/block. Each wave owns
// one n (16 expert-rows) in the GEMM stages. LDS aliased by lifetime:
// bufA = tokens -> encoded; bufB = h -> absdelta. ~78 KB -> 2 blocks/CU.
// GEMV stage (bias + def head): float2 weight loads, (khalf x rgroup) thread
// split, LDS partial reduce -- weights streamed 2x/block for 4 rows.
// ---------------------------------------------------------------------------
template <bool USE_WABC>
__global__ __launch_bounds__(256, 2)
void router_kernel(const float* __restrict__ tokens,
                   const float* __restrict__ encW1, const float* __restrict__ encB1,
                   const float* __restrict__ encW2, const float* __restrict__ encB2,
                   const float* __restrict__ specW1, const float* __restrict__ specB1,
                   const float* __restrict__ specW2,
                   const float* __restrict__ defW1, const float* __restrict__ defB1,
                   const float* __restrict__ defW2, const float* __restrict__ defB2,
                   const int* __restrict__ fiPtr, const int* __restrict__ tkPtr,
                   const float* __restrict__ wabc,
                   float* __restrict__ out, int N) {
    __shared__ float bufA[ROWS * H];    // 32 KB: tokens (first 16 KB) -> encoded
    __shared__ float bufB[ROWS * H];    // 32 KB: h -> absdelta
    __shared__ float s_glob[R * H];     // 2 KB
    __shared__ float s_mabs[R * H];     // 2 KB
    __shared__ float s_bias[R * H];     // 2 KB
    __shared__ float s_pB[2 * R * H];   // 4 KB  GEMV partials (bias)
    __shared__ float s_pD[2 * R * H];   // 4 KB  GEMV partials (def)
    __shared__ float s_logits[ROWS];
    __shared__ float s_dred[R];

    const int tid   = threadIdx.x;
    const int n0    = blockIdx.x * R;
    const int fi    = fiPtr[0];
    const int lane  = tid & 63;
    const int wq    = tid >> 6;        // wave 0..3 == n-row in GEMM stages
    const int j0    = lane * 2;        // 0..126 even
    const int mbase = wq * MW;         // expert-row block for GEMM stages

    // ---- stage 1: load tokens (ROWS*D = 4096 floats) into bufA ----
    {
        const size_t base  = (size_t)n0 * (E * D);
        const size_t total = (size_t)N * (E * D);
        float4* dst = (float4*)bufA;
#pragma unroll
        for (int it = 0; it < 4; it++) {
            int f = tid + it * 256;
            size_t off = base + (size_t)f * 4;
            float4 v = make_float4(0.f, 0.f, 0.f, 0.f);
            if (off + 3 < total) v = *(const float4*)(tokens + off);
            dst[f] = v;
        }
    }
    __syncthreads();

    // ---- stage 2: enc1  h = relu(tok @ W1 + b1), K=64; bufA -> bufB ----
    {
        float acc[MW][2];
#pragma unroll
        for (int m = 0; m < MW; m++) { acc[m][0] = 0.f; acc[m][1] = 0.f; }
#pragma unroll 2
        for (int k = 0; k < D; k += 4) {
            float2 w0 = *(const float2*)(encW1 + (k + 0) * H + j0);
            float2 w1 = *(const float2*)(encW1 + (k + 1) * H + j0);
            float2 w2 = *(const float2*)(encW1 + (k + 2) * H + j0);
            float2 w3 = *(const float2*)(encW1 + (k + 3) * H + j0);
#pragma unroll
            for (int m = 0; m < MW; m++) {
                float4 t = *(const float4*)(bufA + (mbase + m) * D + k);
                acc[m][0] = fmaf(t.w, w3.x, fmaf(t.z, w2.x, fmaf(t.y, w1.x, fmaf(t.x, w0.x, acc[m][0]))));
                acc[m][1] = fmaf(t.w, w3.y, fmaf(t.z, w2.y, fmaf(t.y, w1.y, fmaf(t.x, w0.y, acc[m][1]))));
            }
        }
        float2 b = *(const float2*)(encB1 + j0);
#pragma unroll
        for (int m = 0; m < MW; m++) {
            float2 o;
            o.x = fmaxf(acc[m][0] + b.x, 0.f);
            o.y = fmaxf(acc[m][1] + b.y, 0.f);
            *(float2*)(bufB + (mbase + m) * H + j0) = o;
        }
    }
    __syncthreads();

    // ---- stage 3: enc2  encoded = relu(h @ W2 + b2), K=128; bufB -> bufA ----
    {
        float acc[MW][2];
#pragma unroll
        for (int m = 0; m < MW; m++) { acc[m][0] = 0.f; acc[m][1] = 0.f; }
#pragma unroll 2
        for (int k = 0; k < H; k += 4) {
            float2 w0 = *(const float2*)(encW2 + (k + 0) * H + j0);
            float2 w1 = *(const float2*)(encW2 + (k + 1) * H + j0);
            float2 w2 = *(const float2*)(encW2 + (k + 2) * H + j0);
            float2 w3 = *(const float2*)(encW2 + (k + 3) * H + j0);
#pragma unroll
            for (int m = 0; m < MW; m++) {
                float4 t = *(const float4*)(bufB + (mbase + m) * H + k);
                acc[m][0] = fmaf(t.w, w3.x, fmaf(t.z, w2.x, fmaf(t.y, w1.x, fmaf(t.x, w0.x, acc[m][0]))));
                acc[m][1] = fmaf(t.w, w3.y, fmaf(t.z, w2.y, fmaf(t.y, w1.y, fmaf(t.x, w0.y, acc[m][1]))));
            }
        }
        float2 b = *(const float2*)(encB2 + j0);
#pragma unroll
        for (int m = 0; m < MW; m++) {
            float2 o;
            o.x = fmaxf(acc[m][0] + b.x, 0.f);
            o.y = fmaxf(acc[m][1] + b.y, 0.f);
            *(float2*)(bufA + (mbase + m) * H + j0) = o;
        }
    }
    __syncthreads();

    // ---- stage 4: stats: glob mean, absdelta (bufA -> bufB), mean|delta| ----
    {
        const int r4 = tid >> 6;       // 0..3
        const int cb = tid & 63;
#pragma unroll
        for (int half = 0; half < 2; half++) {
            const int c = cb + half * 64;
            const float* er = bufA + (r4 * E) * H + c;
            float s = 0.f;
#pragma unroll
            for (int e = 0; e < E; e++) s += er[e * H];
            float g  = s * (1.f / 16.f);
            float fc = er[fi * H];
            float ma = 0.f;
#pragma unroll
            for (int e = 0; e < E; e++) {
                float d = er[e * H] - fc;
                float a = fabsf(d);
                bufB[(r4 * E + e) * H + c] = a;
                ma += a;
            }
            s_glob[r4 * H + c] = g;
            s_mabs[r4 * H + c] = ma * (1.f / 16.f);
        }
    }
    __syncthreads();

    // ---- stage 5+7a: GEMV partials: bias (full@Wb + glob@Wc), def head ----
    {
        const int jp = tid & 63;       // j-pair index
        const int jj = jp * 2;
        const int kh = (tid >> 6) & 1; // K-half
        const int rg = tid >> 7;       // r-group (rows rg*2, rg*2+1)
        const int c0 = kh * 64;
        const float* Wb = specW1 + H * H;
        const float* Wc = specW1 + 2 * H * H;
        float accB[2][2] = {{0.f, 0.f}, {0.f, 0.f}};
        float accD[2][2] = {{0.f, 0.f}, {0.f, 0.f}};
        for (int cc = 0; cc < 64; cc++) {
            const int c = c0 + cc;
            float2 wb = *(const float2*)(Wb + c * H + jj);
            float2 wc = *(const float2*)(Wc + c * H + jj);
            float2 d0 = *(const float2*)(defW1 + c * H + jj);
            float2 d1 = *(const float2*)(defW1 + (H + c) * H + jj);
            float2 d2 = *(const float2*)(defW1 + (2 * H + c) * H + jj);
#pragma unroll
            for (int rl = 0; rl < 2; rl++) {
                const int r = rg * 2 + rl;
                float fv = bufA[(r * E + fi) * H + c];
                float gv = s_glob[r * H + c];
                float mv = s_mabs[r * H + c];
                accB[rl][0] = fmaf(fv, wb.x, accB[rl][0]);
                accB[rl][1] = fmaf(fv, wb.y, accB[rl][1]);
                accB[rl][0] = fmaf(gv, wc.x, accB[rl][0]);
                accB[rl][1] = fmaf(gv, wc.y, accB[rl][1]);
                accD[rl][0] = fmaf(fv, d0.x, accD[rl][0]);
                accD[rl][1] = fmaf(fv, d0.y, accD[rl][1]);
                accD[rl][0] = fmaf(gv, d1.x, accD[rl][0]);
                accD[rl][1] = fmaf(gv, d1.y, accD[rl][1]);
                accD[rl][0] = fmaf(mv, d2.x, accD[rl][0]);
                accD[rl][1] = fmaf(mv, d2.y, accD[rl][1]);
            }
        }
#pragma unroll
        for (int rl = 0; rl < 2; rl++) {
            const int r = rg * 2 + rl;
            *(float2*)(s_pB + (kh * R + r) * H + jj) = make_float2(accB[rl][0], accB[rl][1]);
            *(float2*)(s_pD + (kh * R + r) * H + jj) = make_float2(accD[rl][0], accD[rl][1]);
        }
    }
    __syncthreads();

    // ---- stage 5+7b: finalize bias and defer logit (wave wq owns row wq) ----
    {
        float dv = 0.f;
#pragma unroll
        for (int t = 0; t < 2; t++) {
            const int j = lane + t * 64;
            float pb = s_pB[wq * H + j] + s_pB[(R + wq) * H + j];
            s_bias[wq * H + j] = specB1[j] - pb;
            float pd = defB1[j] + s_pD[wq * H + j] + s_pD[(R + wq) * H + j];
            dv += fmaxf(pd, 0.f) * defW2[j];
        }
        dv = waveReduceSum(dv);
        if (lane == 0) s_dred[wq] = dv;
    }
    __syncthreads();

    // ---- stage 6: spec GEMM: spec_h = relu(enc@Wabc + absd@Wd + bias); logits ----
    {
        float acc[MW][2];
#pragma unroll
        for (int m = 0; m < MW; m++) { acc[m][0] = 0.f; acc[m][1] = 0.f; }
        for (int c = 0; c < H; c += 4) {
            float2 wa0, wa1, wa2, wa3;
            if (USE_WABC) {
                wa0 = *(const float2*)(wabc + (c + 0) * H + j0);
                wa1 = *(const float2*)(wabc + (c + 1) * H + j0);
                wa2 = *(const float2*)(wabc + (c + 2) * H + j0);
                wa3 = *(const float2*)(wabc + (c + 3) * H + j0);
            } else {
#pragma unroll
                for (int t = 0; t < 4; t++) {
                    float2 a0 = *(const float2*)(specW1 + (c + t) * H + j0);
                    float2 a1 = *(const float2*)(specW1 + (H + c + t) * H + j0);
                    float2 a2 = *(const float2*)(specW1 + (2 * H + c + t) * H + j0);
                    float2 s2; s2.x = a0.x + a1.x + a2.x; s2.y = a0.y + a1.y + a2.y;
                    if (t == 0) wa0 = s2; else if (t == 1) wa1 = s2; else if (t == 2) wa2 = s2; else wa3 = s2;
                }
            }
            float2 wd0 = *(const float2*)(specW1 + (3 * H + c + 0) * H + j0);
            float2 wd1 = *(const float2*)(specW1 + (3 * H + c + 1) * H + j0);
            float2 wd2 = *(const float2*)(specW1 + (3 * H + c + 2) * H + j0);
            float2 wd3 = *(const float2*)(specW1 + (3 * H + c + 3) * H + j0);
#pragma unroll
            for (int m = 0; m < MW; m++) {
                float4 ev = *(const float4*)(bufA + (mbase + m) * H + c);
                float4 av = *(const float4*)(bufB + (mbase + m) * H + c);
                float a0 = acc[m][0], a1 = acc[m][1];
                a0 = fmaf(ev.x, wa0.x, a0); a0 = fmaf(ev.y, wa1.x, a0);
                a0 = fmaf(ev.z, wa2.x, a0); a0 = fmaf(ev.w, wa3.x, a0);
                a0 = fmaf(av.x, wd0.x, a0); a0 = fmaf(av.y, wd1.x, a0);
                a0 = fmaf(av.z, wd2.x, a0); a0 = fmaf(av.w, wd3.x, a0);
                a1 = fmaf(ev.x, wa0.y, a1); a1 = fmaf(ev.y, wa1.y, a1);
                a1 = fmaf(ev.z, wa2.y, a1); a1 = fmaf(ev.w, wa3.y, a1);
                a1 = fmaf(av.x, wd0.y, a1); a1 = fmaf(av.y, wd1.y, a1);
                a1 = fmaf(av.z, wd2.y, a1); a1 = fmaf(av.w, wd3.y, a1);
                acc[m][0] = a0; acc[m][1] = a1;
            }
        }
        float2 bn = *(const float2*)(s_bias + wq * H + j0);
        float2 w2 = *(const float2*)(specW2 + j0);
#pragma unroll
        for (int m = 0; m < MW; m++) {
            float h0 = fmaxf(acc[m][0] + bn.x, 0.f);
            float h1 = fmaxf(acc[m][1] + bn.y, 0.f);
            float p  = h0 * w2.x + h1 * w2.y;   // spec_b2 dropped: softmax shift-invariant
            p = waveReduceSum(p);
            if (lane == 0) s_logits[mbase + m] = p;
        }
    }
    __syncthreads();

    // ---- stage 8: finalize (R threads: one per n-row) ----
    if (tid < R && (n0 + tid) < N) {
        const int r = tid;
        const int n = n0 + r;
        // defer prob
        float s = s_dred[r] + defB2[0];
        out[(size_t)N * E + n] = 1.f / (1.f + expf(-s));
        // top-k selection (fi excluded; strict > matches lax.top_k tie order)
        int k = tkPtr[0];
        if (k < 1) k = 1;
        if (k > E - 1) k = E - 1;
        unsigned chosen = 0u;
        for (int kk = 0; kk < k; kk++) {
            float bv = -INFINITY;
            int bi = 0;
            for (int e = 0; e < E; e++) {
                if (e == fi || ((chosen >> e) & 1u)) continue;
                float v = s_logits[r * E + e];
                if (v > bv) { bv = v; bi = e; }
            }
            chosen |= (1u << bi);
        }
        float mx = -INFINITY;
        for (int e = 0; e < E; e++)
            if ((chosen >> e) & 1u) { float v = s_logits[r * E + e]; if (v > mx) mx = v; }
        float ssum = 0.f;
        for (int e = 0; e < E; e++)
            if ((chosen >> e) & 1u) ssum += expf(s_logits[r * E + e] - mx);
        float inv = 1.f / ssum;
        for (int e = 0; e < E; e++) {
            float wv = 0.f;
            if ((chosen >> e) & 1u) wv = expf(s_logits[r * E + e] - mx) * inv;
            out[(size_t)n * E + e] = wv;
        }
    }
}

extern "C" void kernel_launch(void* const* d_in, const int* in_sizes, int n_in,
                              void* d_out, int out_size, void* d_ws, size_t ws_size,
                              hipStream_t stream) {
    (void)n_in; (void)out_size;
    const float* tokens = (const float*)d_in[0];
    const float* encW1  = (const float*)d_in[1];
    const float* encB1  = (const float*)d_in[2];
    const float* encW2  = (const float*)d_in[3];
    const float* encB2  = (const float*)d_in[4];
    const float* specW1 = (const float*)d_in[5];
    const float* specB1 = (const float*)d_in[6];
    const float* specW2 = (const float*)d_in[7];
    // d_in[8] = spec_b2 (unused: softmax is shift-invariant)
    const float* defW1  = (const float*)d_in[9];
    const float* defB1  = (const float*)d_in[10];
    const float* defW2  = (const float*)d_in[11];
    const float* defB2  = (const float*)d_in[12];
    const int*   fiPtr  = (const int*)d_in[13];
    const int*   tkPtr  = (const int*)d_in[14];
    float* out = (float*)d_out;

    const int N = in_sizes[0] / (E * D);
    const int grid = (N + R - 1) / R;
    const bool useWs = (d_ws != nullptr) && (ws_size >= (size_t)(H * H * sizeof(float)));

    if (useWs) {
        wabc_prep<<<(H * H + 255) / 256, 256, 0, stream>>>(specW1, (float*)d_ws);
        router_kernel<true><<<grid, 256, 0, stream>>>(
            tokens, encW1, encB1, encW2, encB2, specW1, specB1, specW2,
            defW1, defB1, defW2, defB2, fiPtr, tkPtr, (const float*)d_ws, out, N);
    } else {
        router_kernel<false><<<grid, 256, 0, stream>>>(
            tokens, encW1, encB1, encW2, encB2, specW1, specB1, specW2,
            defW1, defB1, defW2, defB2, fiPtr, tkPtr, nullptr, out, N);
    }
}